// Round 2
// baseline (1949.703 us; speedup 1.0000x reference)
//
#include <hip/hip_runtime.h>

// Problem: B=8, L=1024, D=512, H=8, DH=64.  All float tensors f32, masks int32.
// Outputs concatenated: out [8,1024,512] then attention [8,8,1024,1024], f32.
#define BB 8
#define LL 1024
#define DD 512
#define HH 8
#define DHH 64

__device__ __forceinline__ void load8_f32(const float* p, float o[8]) {
    float4 a = *reinterpret_cast<const float4*>(p);
    float4 b = *reinterpret_cast<const float4*>(p + 4);
    o[0]=a.x; o[1]=a.y; o[2]=a.z; o[3]=a.w; o[4]=b.x; o[5]=b.y; o[6]=b.z; o[7]=b.w;
}

// ---------------- mask packing: int32 0/1 -> bitset (1 bit per element) -----
__global__ __launch_bounds__(256) void maskpack_kernel(
    const int* __restrict__ am, const int* __restrict__ sm,
    unsigned* __restrict__ ab, unsigned* __restrict__ sb)
{
    const int* src = blockIdx.y ? sm : am;
    unsigned* dst  = blockIdx.y ? sb : ab;
    const int g = blockIdx.x * 256 + threadIdx.x;
    unsigned long long bm = __ballot(src[g] != 0);
    const int l = threadIdx.x & 63;
    if (l == 0)  dst[g >> 5] = (unsigned)bm;
    if (l == 32) dst[g >> 5] = (unsigned)(bm >> 32);
}

// ---------------- Y[M,N] = A[M,K] @ W[N,K]^T  (K=N=512), f32 accumulate ----
__device__ __forceinline__ void gemm_abt_body(const float* __restrict__ A,
                                              const float* __restrict__ W,
                                              float* __restrict__ Y)
{
    __shared__ float As[32 * 68];
    __shared__ float Bs[32 * 68];
    const int t  = threadIdx.x;
    const int m0 = blockIdx.y * 64;
    const int n0 = blockIdx.x * 64;
    const int tm = (t & 15) * 4;
    const int tn = (t >> 4) * 4;
    const int lr = t >> 2;         // 0..63 tile row
    const int lc = (t & 3) * 8;    // 0..24 k-chunk
    float acc[4][4] = {{0.f}};
    for (int k0 = 0; k0 < 512; k0 += 32) {
        float a8[8], b8[8];
        load8_f32(A + (size_t)(m0 + lr) * 512 + k0 + lc, a8);
        load8_f32(W + (size_t)(n0 + lr) * 512 + k0 + lc, b8);
        __syncthreads();
        #pragma unroll
        for (int e = 0; e < 8; e++) {
            As[(lc + e) * 68 + lr] = a8[e];
            Bs[(lc + e) * 68 + lr] = b8[e];
        }
        __syncthreads();
        #pragma unroll
        for (int k = 0; k < 32; k++) {
            const float4 av = *reinterpret_cast<const float4*>(&As[k * 68 + tm]);
            const float4 bv = *reinterpret_cast<const float4*>(&Bs[k * 68 + tn]);
            const float a_[4] = {av.x, av.y, av.z, av.w};
            const float b_[4] = {bv.x, bv.y, bv.z, bv.w};
            #pragma unroll
            for (int mi = 0; mi < 4; mi++)
                #pragma unroll
                for (int ni = 0; ni < 4; ni++)
                    acc[mi][ni] += a_[mi] * b_[ni];
        }
    }
    #pragma unroll
    for (int mi = 0; mi < 4; mi++) {
        float4 o; o.x = acc[mi][0]; o.y = acc[mi][1]; o.z = acc[mi][2]; o.w = acc[mi][3];
        *reinterpret_cast<float4*>(&Y[(size_t)(m0 + tm + mi) * 512 + n0 + tn]) = o;
    }
}

__global__ __launch_bounds__(256) void proj_kernel(
    const float* q, const float* k, const float* v,
    const float* wq, const float* wk, const float* wv,
    float* Q, float* K, float* V)
{
    const float* A; const float* W; float* Y;
    if (blockIdx.z == 0)      { A = q; W = wq; Y = Q; }
    else if (blockIdx.z == 1) { A = k; W = wk; Y = K; }
    else                      { A = v; W = wv; Y = V; }
    gemm_abt_body(A, W, Y);
}

__global__ __launch_bounds__(256) void outproj_kernel(
    const float* CTX, const float* wo, float* Y)
{
    gemm_abt_body(CTX, wo, Y);
}

// ---------------- fused scores + masked softmax -> f32 attention ------------
__global__ __launch_bounds__(256) void scores_kernel(
    const float* __restrict__ Q, const float* __restrict__ K,
    const unsigned* __restrict__ ab, const unsigned* __restrict__ sb,
    float* __restrict__ attn)
{
    __shared__ float qs[16 * 64];
    __shared__ float redm[16][4];
    __shared__ float reds[16][4];
    const int t   = threadIdx.x;
    const int bh  = blockIdx.y;
    const int b   = bh >> 3, h = bh & 7;
    const int qi0 = blockIdx.x * 16;
    {
        const int i = t >> 4, d = (t & 15) * 4;
        *reinterpret_cast<float4*>(&qs[i * 64 + d]) =
            *reinterpret_cast<const float4*>(&Q[(size_t)(b * LL + qi0 + i) * DD + h * DHH + d]);
    }
    __syncthreads();

    float s[16][4];
    #pragma unroll
    for (int i = 0; i < 16; i++) { s[i][0] = 0.f; s[i][1] = 0.f; s[i][2] = 0.f; s[i][3] = 0.f; }

    #pragma unroll
    for (int jj = 0; jj < 4; jj++) {
        const int j = t * 4 + jj;
        const float* kp = &K[(size_t)(b * LL + j) * DD + h * DHH];
        #pragma unroll
        for (int half = 0; half < 2; half++) {
            float4 kr[8];
            #pragma unroll
            for (int d4 = 0; d4 < 8; d4++)
                kr[d4] = *reinterpret_cast<const float4*>(&kp[(half * 8 + d4) * 4]);
            #pragma unroll
            for (int i = 0; i < 16; i++) {
                float acc = 0.f;
                #pragma unroll
                for (int d4 = 0; d4 < 8; d4++) {
                    const float4 qv = *reinterpret_cast<const float4*>(&qs[i * 64 + (half * 8 + d4) * 4]);
                    acc += qv.x * kr[d4].x + qv.y * kr[d4].y + qv.z * kr[d4].z + qv.w * kr[d4].w;
                }
                s[i][jj] += acc;
            }
        }
    }

    const int wword = t >> 3;
    const int nibsh = (t & 7) * 4;
    const int lane = t & 63, wid = t >> 6;

    // scale + attn_mask -> -1e30, then row max (wave shuffle + cross-wave LDS)
    #pragma unroll
    for (int i = 0; i < 16; i++) {
        const size_t row = (size_t)(b * LL + qi0 + i);
        const unsigned anib = (ab[row * 32 + wword] >> nibsh) & 0xFu;
        #pragma unroll
        for (int jj = 0; jj < 4; jj++) {
            const float x = s[i][jj] * 0.125f;
            s[i][jj] = ((anib >> jj) & 1u) ? -1e30f : x;
        }
        float m = fmaxf(fmaxf(s[i][0], s[i][1]), fmaxf(s[i][2], s[i][3]));
        #pragma unroll
        for (int off = 32; off > 0; off >>= 1) m = fmaxf(m, __shfl_xor(m, off));
        if (lane == 0) redm[i][wid] = m;
    }
    __syncthreads();
    float fm[16];
    #pragma unroll
    for (int i = 0; i < 16; i++)
        fm[i] = fmaxf(fmaxf(redm[i][0], redm[i][1]), fmaxf(redm[i][2], redm[i][3]));

    // exp + row sum
    #pragma unroll
    for (int i = 0; i < 16; i++) {
        float l = 0.f;
        #pragma unroll
        for (int jj = 0; jj < 4; jj++) {
            const float p = __expf(s[i][jj] - fm[i]);   // masked: exp(-1e30) -> 0
            s[i][jj] = p; l += p;
        }
        #pragma unroll
        for (int off = 32; off > 0; off >>= 1) l += __shfl_xor(l, off);
        if (lane == 0) reds[i][wid] = l;
    }
    __syncthreads();

    // normalize, softmax_mask -> 0, store f32 (coalesced float4)
    #pragma unroll
    for (int i = 0; i < 16; i++) {
        const float inv = 1.f / (reds[i][0] + reds[i][1] + reds[i][2] + reds[i][3]);
        const size_t row = (size_t)(b * LL + qi0 + i);
        const unsigned snib = (sb[row * 32 + wword] >> nibsh) & 0xFu;
        float4 o;
        o.x = ((snib >> 0) & 1u) ? 0.f : s[i][0] * inv;
        o.y = ((snib >> 1) & 1u) ? 0.f : s[i][1] * inv;
        o.z = ((snib >> 2) & 1u) ? 0.f : s[i][2] * inv;
        o.w = ((snib >> 3) & 1u) ? 0.f : s[i][3] * inv;
        *reinterpret_cast<float4*>(&attn[((size_t)bh * LL + qi0 + i) * LL + t * 4]) = o;
    }
}

// ---------------- context = attention @ V  (per head) ----------------------
__global__ __launch_bounds__(256) void context_kernel(
    const float* __restrict__ P, const float* __restrict__ V,
    float* __restrict__ CTX)
{
    __shared__ float Ps[32 * 68];
    __shared__ float Vs[32 * 68];
    const int t  = threadIdx.x;
    const int bh = blockIdx.y, b = bh >> 3, h = bh & 7;
    const int i0 = blockIdx.x * 64;
    const int tm = (t & 15) * 4, tn = (t >> 4) * 4;
    const int lr = t >> 2, lc = (t & 3) * 8;   // P tile 64x32
    const int vr = t >> 3, vc = (t & 7) * 8;   // V tile 32x64
    const float* Pb = P + ((size_t)bh * LL + i0) * LL;
    const float* Vb = V + (size_t)b * LL * DD + h * DHH;
    float acc[4][4] = {{0.f}};
    for (int j0 = 0; j0 < LL; j0 += 32) {
        float a8[8], b8[8];
        load8_f32(Pb + (size_t)lr * LL + j0 + lc, a8);
        load8_f32(Vb + (size_t)(j0 + vr) * DD + vc, b8);
        __syncthreads();
        #pragma unroll
        for (int e = 0; e < 8; e++) Ps[(lc + e) * 68 + lr] = a8[e];
        #pragma unroll
        for (int e = 0; e < 8; e++) Vs[vr * 68 + vc + e] = b8[e];
        __syncthreads();
        #pragma unroll
        for (int k = 0; k < 32; k++) {
            const float4 av = *reinterpret_cast<const float4*>(&Ps[k * 68 + tm]);
            const float4 bv = *reinterpret_cast<const float4*>(&Vs[k * 68 + tn]);
            const float a_[4] = {av.x, av.y, av.z, av.w};
            const float b_[4] = {bv.x, bv.y, bv.z, bv.w};
            #pragma unroll
            for (int mi = 0; mi < 4; mi++)
                #pragma unroll
                for (int ni = 0; ni < 4; ni++)
                    acc[mi][ni] += a_[mi] * b_[ni];
        }
    }
    #pragma unroll
    for (int mi = 0; mi < 4; mi++) {
        float4 o; o.x = acc[mi][0]; o.y = acc[mi][1]; o.z = acc[mi][2]; o.w = acc[mi][3];
        *reinterpret_cast<float4*>(&CTX[(size_t)(b * LL + i0 + tm + mi) * DD + h * DHH + tn]) = o;
    }
}

// ---------------- residual + LayerNorm -> f32 out ---------------------------
__global__ __launch_bounds__(256) void ln_kernel(
    const float* __restrict__ X, const float* __restrict__ R,
    float* __restrict__ out)
{
    __shared__ float rs[4], rq[4];
    const int r = blockIdx.x, t = threadIdx.x;
    const float* xr = X + (size_t)r * 512;
    const float* rr = R + (size_t)r * 512;
    const float2 xv = *reinterpret_cast<const float2*>(&xr[2 * t]);
    const float2 rv = *reinterpret_cast<const float2*>(&rr[2 * t]);
    const float x0 = xv.x + rv.x;
    const float x1 = xv.y + rv.y;
    float s = x0 + x1, q = x0 * x0 + x1 * x1;
    #pragma unroll
    for (int off = 32; off > 0; off >>= 1) { s += __shfl_xor(s, off); q += __shfl_xor(q, off); }
    if ((t & 63) == 0) { rs[t >> 6] = s; rq[t >> 6] = q; }
    __syncthreads();
    s = rs[0] + rs[1] + rs[2] + rs[3];
    q = rq[0] + rq[1] + rq[2] + rq[3];
    const float mean = s * (1.f / 512.f);
    const float var  = q * (1.f / 512.f) - mean * mean;
    const float rstd = rsqrtf(var + 1e-5f);
    float2 o;
    o.x = (x0 - mean) * rstd;
    o.y = (x1 - mean) * rstd;
    *reinterpret_cast<float2*>(&out[(size_t)r * 512 + 2 * t]) = o;
}

extern "C" void kernel_launch(void* const* d_in, const int* in_sizes, int n_in,
                              void* d_out, int out_size, void* d_ws, size_t ws_size,
                              hipStream_t stream)
{
    const float* q  = (const float*)d_in[0];
    const float* k  = (const float*)d_in[1];
    const float* v  = (const float*)d_in[2];
    const int*   am = (const int*)d_in[3];
    const int*   sm = (const int*)d_in[4];
    const float* wq = (const float*)d_in[5];
    const float* wk = (const float*)d_in[6];
    const float* wv = (const float*)d_in[7];
    const float* wo = (const float*)d_in[8];

    float* out  = (float*)d_out;                         // [8192, 512]
    float* attn = out + (size_t)BB * LL * DD;            // [64, 1024, 1024]

    float* ws    = (float*)d_ws;
    float* Qf    = ws;                       // 4M f32 each
    float* Kf    = ws + 1 * 4194304;
    float* Vf    = ws + 2 * 4194304;
    float* CTXf  = ws + 3 * 4194304;
    unsigned* ab = (unsigned*)(ws + 4 * 4194304);  // 256K words
    unsigned* sb = ab + 262144;
    float* X2f   = Qf;  // Q is dead after scores_kernel; reuse for out-proj

    maskpack_kernel<<<dim3(32768, 2, 1), 256, 0, stream>>>(am, sm, ab, sb);
    proj_kernel<<<dim3(8, 128, 3), 256, 0, stream>>>(q, k, v, wq, wk, wv, Qf, Kf, Vf);
    scores_kernel<<<dim3(64, 64, 1), 256, 0, stream>>>(Qf, Kf, ab, sb, attn);
    context_kernel<<<dim3(16, 64, 1), 256, 0, stream>>>(attn, Vf, CTXf);
    outproj_kernel<<<dim3(8, 128, 1), 256, 0, stream>>>(CTXf, wo, X2f);
    ln_kernel<<<dim3(8192, 1, 1), 256, 0, stream>>>(X2f, q, out);
}

// Round 3
// 681.334 us; speedup vs baseline: 2.8616x; 2.8616x over previous
//
#include <hip/hip_runtime.h>

// B=8, L=1024, D=512, H=8, DH=64. Inputs f32 (+ int32 masks), outputs f32:
// out [8,1024,512] then attention [8,8,1024,1024] concatenated in d_out.
// Internally: bf16 MFMA (16x16x32) for all GEMM-shaped work, f32 accumulate.
#define BB 8
#define LL 1024
#define DD 512
#define HH 8

typedef __attribute__((ext_vector_type(8))) short bf16x8;
typedef __attribute__((ext_vector_type(4))) float f32x4;

__device__ __forceinline__ unsigned short f2bf(float f) {
    union { float f; unsigned u; } c; c.f = f;
    unsigned u = c.u + 0x7fffu + ((c.u >> 16) & 1u);  // RNE
    return (unsigned short)(u >> 16);
}

// ---------------- f32 -> bf16 casts for q,k,v and the 4 weights -------------
__global__ __launch_bounds__(256) void cast_kernel(
    const float* q, const float* k, const float* v,
    const float* wq, const float* wk, const float* wv, const float* wo,
    unsigned short* qb, unsigned short* kb, unsigned short* vb,
    unsigned short* wqb, unsigned short* wkb, unsigned short* wvb, unsigned short* wob)
{
    const float* src; unsigned short* dst; int n;
    switch (blockIdx.z) {
        case 0: src = q;  dst = qb;  n = 4194304; break;
        case 1: src = k;  dst = kb;  n = 4194304; break;
        case 2: src = v;  dst = vb;  n = 4194304; break;
        case 3: src = wq; dst = wqb; n = 262144;  break;
        case 4: src = wk; dst = wkb; n = 262144;  break;
        case 5: src = wv; dst = wvb; n = 262144;  break;
        default: src = wo; dst = wob; n = 262144; break;
    }
    const int g = (blockIdx.x * 256 + threadIdx.x) * 8;
    if (g >= n) return;
    const float4 a = *reinterpret_cast<const float4*>(src + g);
    const float4 b = *reinterpret_cast<const float4*>(src + g + 4);
    uint4 o;
    o.x = (unsigned)f2bf(a.x) | ((unsigned)f2bf(a.y) << 16);
    o.y = (unsigned)f2bf(a.z) | ((unsigned)f2bf(a.w) << 16);
    o.z = (unsigned)f2bf(b.x) | ((unsigned)f2bf(b.y) << 16);
    o.w = (unsigned)f2bf(b.z) | ((unsigned)f2bf(b.w) << 16);
    *reinterpret_cast<uint4*>(dst + g) = o;
}

// ---------------- mask packing: int32 0/1 -> bitset -------------------------
__global__ __launch_bounds__(256) void maskpack_kernel(
    const int* __restrict__ am, const int* __restrict__ sm,
    unsigned* __restrict__ ab, unsigned* __restrict__ sb)
{
    const int* src = blockIdx.y ? sm : am;
    unsigned* dst  = blockIdx.y ? sb : ab;
    const int g = blockIdx.x * 256 + threadIdx.x;
    unsigned long long bm = __ballot(src[g] != 0);
    const int l = threadIdx.x & 63;
    if (l == 0)  dst[g >> 5] = (unsigned)bm;
    if (l == 32) dst[g >> 5] = (unsigned)(bm >> 32);
}

// ---------------- bf16 MFMA GEMM: Y[M,N] = A[M,K] @ W[N,K]^T ---------------
// M=8192, N=512, K=512. 128x128 tile, BK=32, 4 waves in 2x2, 64x64 per wave.
template<bool OUTBF>
__device__ __forceinline__ void gemm_mfma_body(
    const unsigned short* __restrict__ A, const unsigned short* __restrict__ W,
    void* __restrict__ Yv)
{
    __shared__ unsigned short As[128 * 40];   // row stride 40 bf16 (80 B)
    __shared__ unsigned short Bs[128 * 40];
    const int t = threadIdx.x, w = t >> 6, lane = t & 63;
    const int ln15 = lane & 15, quad = lane >> 4;
    const int wm = w & 1, wn = w >> 1;
    const int m0 = blockIdx.y * 128, n0 = blockIdx.x * 128;
    f32x4 acc[4][4];
    #pragma unroll
    for (int i = 0; i < 4; i++)
        #pragma unroll
        for (int j = 0; j < 4; j++) acc[i][j] = (f32x4){0.f, 0.f, 0.f, 0.f};

    for (int k0 = 0; k0 < 512; k0 += 32) {
        uint4 ga[2], gb[2];
        #pragma unroll
        for (int i = 0; i < 2; i++) {
            const int u = t + i * 256, row = u >> 2, ch = (u & 3) * 8;
            ga[i] = *reinterpret_cast<const uint4*>(&A[(size_t)(m0 + row) * 512 + k0 + ch]);
            gb[i] = *reinterpret_cast<const uint4*>(&W[(size_t)(n0 + row) * 512 + k0 + ch]);
        }
        if (k0) __syncthreads();
        #pragma unroll
        for (int i = 0; i < 2; i++) {
            const int u = t + i * 256, row = u >> 2, ch = (u & 3) * 8;
            *reinterpret_cast<uint4*>(&As[row * 40 + ch]) = ga[i];
            *reinterpret_cast<uint4*>(&Bs[row * 40 + ch]) = gb[i];
        }
        __syncthreads();
        bf16x8 af[4], bf_[4];
        #pragma unroll
        for (int s = 0; s < 4; s++) {
            af[s]  = *reinterpret_cast<const bf16x8*>(&As[(wm * 64 + s * 16 + ln15) * 40 + quad * 8]);
            bf_[s] = *reinterpret_cast<const bf16x8*>(&Bs[(wn * 64 + s * 16 + ln15) * 40 + quad * 8]);
        }
        #pragma unroll
        for (int sm_ = 0; sm_ < 4; sm_++)
            #pragma unroll
            for (int sn_ = 0; sn_ < 4; sn_++)
                acc[sm_][sn_] = __builtin_amdgcn_mfma_f32_16x16x32_bf16(
                    af[sm_], bf_[sn_], acc[sm_][sn_], 0, 0, 0);
    }
    #pragma unroll
    for (int sm_ = 0; sm_ < 4; sm_++)
        #pragma unroll
        for (int sn_ = 0; sn_ < 4; sn_++)
            #pragma unroll
            for (int r = 0; r < 4; r++) {
                const int row = m0 + wm * 64 + sm_ * 16 + quad * 4 + r;
                const int col = n0 + wn * 64 + sn_ * 16 + ln15;
                if (OUTBF)
                    ((unsigned short*)Yv)[(size_t)row * 512 + col] = f2bf(acc[sm_][sn_][r]);
                else
                    ((float*)Yv)[(size_t)row * 512 + col] = acc[sm_][sn_][r];
            }
}

__global__ __launch_bounds__(256) void gemm3_kernel(
    const unsigned short* a0, const unsigned short* a1, const unsigned short* a2,
    const unsigned short* w0, const unsigned short* w1, const unsigned short* w2,
    unsigned short* y0, unsigned short* y1, unsigned short* y2)
{
    const unsigned short *A, *W; unsigned short* Y;
    if (blockIdx.z == 0)      { A = a0; W = w0; Y = y0; }
    else if (blockIdx.z == 1) { A = a1; W = w1; Y = y1; }
    else                      { A = a2; W = w2; Y = y2; }
    gemm_mfma_body<true>(A, W, Y);
}

__global__ __launch_bounds__(256) void gemm1_kernel(
    const unsigned short* A, const unsigned short* W, float* Y)
{
    gemm_mfma_body<false>(A, W, Y);
}

// ---------------- V transpose: [B,L,D] slice -> Vt[(b*8+h)*64+dh][token] ----
__global__ __launch_bounds__(256) void vtrans_kernel(
    const unsigned short* __restrict__ Vb, unsigned short* __restrict__ Vt)
{
    __shared__ unsigned short tile[64 * 72];
    const int t = threadIdx.x;
    const int tt = blockIdx.x, h = blockIdx.y, b = blockIdx.z;
    #pragma unroll
    for (int i = 0; i < 2; i++) {
        const int u = t + i * 256, row = u >> 3, ch = (u & 7) * 8;
        *reinterpret_cast<uint4*>(&tile[row * 72 + ch]) =
            *reinterpret_cast<const uint4*>(&Vb[(size_t)(b * 1024 + tt * 64 + row) * 512 + h * 64 + ch]);
    }
    __syncthreads();
    #pragma unroll
    for (int i = 0; i < 2; i++) {
        const int u = t + i * 256, dh = u >> 3, ch = (u & 7) * 8;
        unsigned short r8[8];
        #pragma unroll
        for (int e = 0; e < 8; e++) r8[e] = tile[(ch + e) * 72 + dh];
        uint4 o;
        o.x = (unsigned)r8[0] | ((unsigned)r8[1] << 16);
        o.y = (unsigned)r8[2] | ((unsigned)r8[3] << 16);
        o.z = (unsigned)r8[4] | ((unsigned)r8[5] << 16);
        o.w = (unsigned)r8[6] | ((unsigned)r8[7] << 16);
        *reinterpret_cast<uint4*>(&Vt[(size_t)((b * 8 + h) * 64 + dh) * 1024 + tt * 64 + ch]) = o;
    }
}

// ---------------- fused flash attention: scores+softmax+masks+PV ------------
// grid (16 qtiles, 64 bh), 256 thr = 4 waves; wave owns 16 q-rows.
__global__ __launch_bounds__(256) void fattn_kernel(
    const unsigned short* __restrict__ Qb, const unsigned short* __restrict__ Kb,
    const unsigned short* __restrict__ Vt,
    const unsigned* __restrict__ ab, const unsigned* __restrict__ sb,
    float* __restrict__ attn, unsigned short* __restrict__ CTX)
{
    __shared__ unsigned short Pt[4][16 * 72];   // per-wave P tile, stride 72
    const int t = threadIdx.x, w = t >> 6, lane = t & 63;
    const int ln15 = lane & 15, quad = lane >> 4;
    const int bh = blockIdx.y, b = bh >> 3, h = bh & 7;
    const int qbase = blockIdx.x * 64 + w * 16;

    // Q A-fragments (m=ln15, k=quad*8+j), held all kernel
    const size_t qoff = ((size_t)(b * 1024) + qbase + ln15) * 512 + h * 64 + quad * 8;
    const bf16x8 aq0 = *reinterpret_cast<const bf16x8*>(Qb + qoff);
    const bf16x8 aq1 = *reinterpret_cast<const bf16x8*>(Qb + qoff + 32);

    // mask row word-offsets for the 4 C-layout rows this lane reduces
    size_t mrow[4];
    #pragma unroll
    for (int r = 0; r < 4; r++)
        mrow[r] = ((size_t)(b * 1024) + qbase + quad * 4 + r) * 32;

    float m[4], l[4];
    #pragma unroll
    for (int r = 0; r < 4; r++) { m[r] = -1e30f; l[r] = 0.f; }

    // ---- pass 1: online (m, l) over K tiles ----
    for (int kt = 0; kt < 16; kt++) {
        f32x4 acc[4];
        #pragma unroll
        for (int sub = 0; sub < 4; sub++) {
            const size_t koff = ((size_t)(b * 1024) + kt * 64 + sub * 16 + ln15) * 512 + h * 64 + quad * 8;
            const bf16x8 bk0 = *reinterpret_cast<const bf16x8*>(Kb + koff);
            const bf16x8 bk1 = *reinterpret_cast<const bf16x8*>(Kb + koff + 32);
            f32x4 c = __builtin_amdgcn_mfma_f32_16x16x32_bf16(aq0, bk0, (f32x4){0.f,0.f,0.f,0.f}, 0, 0, 0);
            acc[sub] = __builtin_amdgcn_mfma_f32_16x16x32_bf16(aq1, bk1, c, 0, 0, 0);
        }
        #pragma unroll
        for (int r = 0; r < 4; r++) {
            const unsigned w0 = ab[mrow[r] + kt * 2], w1 = ab[mrow[r] + kt * 2 + 1];
            float s[4];
            #pragma unroll
            for (int sub = 0; sub < 4; sub++) {
                const int cb = sub * 16 + ln15;
                const unsigned msk = ((cb & 32 ? w1 : w0) >> (cb & 31)) & 1u;
                s[sub] = msk ? -1e30f : acc[sub][r] * 0.125f;
            }
            const float tm = fmaxf(fmaxf(s[0], s[1]), fmaxf(s[2], s[3]));
            const float mn = fmaxf(m[r], tm);
            l[r] = l[r] * __expf(m[r] - mn)
                 + __expf(s[0] - mn) + __expf(s[1] - mn)
                 + __expf(s[2] - mn) + __expf(s[3] - mn);
            m[r] = mn;
        }
    }
    // cross-lane combine over the 16 columns (lane bits 0..3)
    float invl[4];
    #pragma unroll
    for (int r = 0; r < 4; r++) {
        #pragma unroll
        for (int off = 1; off < 16; off <<= 1) {
            const float mo = __shfl_xor(m[r], off);
            const float lo = __shfl_xor(l[r], off);
            const float mn = fmaxf(m[r], mo);
            l[r] = l[r] * __expf(m[r] - mn) + lo * __expf(mo - mn);
            m[r] = mn;
        }
        invl[r] = 1.f / l[r];
    }

    // ---- pass 2: recompute, write attention, accumulate O = P @ V ----
    f32x4 o[4];
    #pragma unroll
    for (int sn = 0; sn < 4; sn++) o[sn] = (f32x4){0.f, 0.f, 0.f, 0.f};
    unsigned short* Pw = Pt[w];

    for (int kt = 0; kt < 16; kt++) {
        f32x4 acc[4];
        #pragma unroll
        for (int sub = 0; sub < 4; sub++) {
            const size_t koff = ((size_t)(b * 1024) + kt * 64 + sub * 16 + ln15) * 512 + h * 64 + quad * 8;
            const bf16x8 bk0 = *reinterpret_cast<const bf16x8*>(Kb + koff);
            const bf16x8 bk1 = *reinterpret_cast<const bf16x8*>(Kb + koff + 32);
            f32x4 c = __builtin_amdgcn_mfma_f32_16x16x32_bf16(aq0, bk0, (f32x4){0.f,0.f,0.f,0.f}, 0, 0, 0);
            acc[sub] = __builtin_amdgcn_mfma_f32_16x16x32_bf16(aq1, bk1, c, 0, 0, 0);
        }
        #pragma unroll
        for (int r = 0; r < 4; r++) {
            const unsigned a0 = ab[mrow[r] + kt * 2], a1 = ab[mrow[r] + kt * 2 + 1];
            const unsigned s0 = sb[mrow[r] + kt * 2], s1 = sb[mrow[r] + kt * 2 + 1];
            #pragma unroll
            for (int sub = 0; sub < 4; sub++) {
                const int cb = sub * 16 + ln15;
                const unsigned amsk = ((cb & 32 ? a1 : a0) >> (cb & 31)) & 1u;
                const unsigned smsk = ((cb & 32 ? s1 : s0) >> (cb & 31)) & 1u;
                const float sc = amsk ? -1e30f : acc[sub][r] * 0.125f;
                float a = __expf(sc - m[r]) * invl[r];
                a = smsk ? 0.f : a;
                attn[((size_t)bh * 1024 + qbase + quad * 4 + r) * 1024 + kt * 64 + cb] = a;
                Pw[(quad * 4 + r) * 72 + cb] = f2bf(a);
            }
        }
        __syncthreads();
        const bf16x8 pa0 = *reinterpret_cast<const bf16x8*>(&Pw[ln15 * 72 + quad * 8]);
        const bf16x8 pa1 = *reinterpret_cast<const bf16x8*>(&Pw[ln15 * 72 + 32 + quad * 8]);
        #pragma unroll
        for (int sn = 0; sn < 4; sn++) {
            const size_t voff = ((size_t)bh * 64 + sn * 16 + ln15) * 1024 + kt * 64 + quad * 8;
            const bf16x8 vb0 = *reinterpret_cast<const bf16x8*>(Vt + voff);
            const bf16x8 vb1 = *reinterpret_cast<const bf16x8*>(Vt + voff + 32);
            o[sn] = __builtin_amdgcn_mfma_f32_16x16x32_bf16(pa0, vb0, o[sn], 0, 0, 0);
            o[sn] = __builtin_amdgcn_mfma_f32_16x16x32_bf16(pa1, vb1, o[sn], 0, 0, 0);
        }
        __syncthreads();
    }
    // epilogue: CTX bf16 [B,L,D]
    #pragma unroll
    for (int sn = 0; sn < 4; sn++)
        #pragma unroll
        for (int r = 0; r < 4; r++)
            CTX[((size_t)(b * 1024) + qbase + quad * 4 + r) * 512 + h * 64 + sn * 16 + ln15] =
                f2bf(o[sn][r]);
}

// ---------------- residual + LayerNorm -> f32 out ---------------------------
__global__ __launch_bounds__(256) void ln_kernel(
    const float* __restrict__ X, const float* __restrict__ R,
    float* __restrict__ out)
{
    __shared__ float rs[4], rq[4];
    const int r = blockIdx.x, t = threadIdx.x;
    const float2 xv = *reinterpret_cast<const float2*>(&X[(size_t)r * 512 + 2 * t]);
    const float2 rv = *reinterpret_cast<const float2*>(&R[(size_t)r * 512 + 2 * t]);
    const float x0 = xv.x + rv.x, x1 = xv.y + rv.y;
    float s = x0 + x1, q = x0 * x0 + x1 * x1;
    #pragma unroll
    for (int off = 32; off > 0; off >>= 1) { s += __shfl_xor(s, off); q += __shfl_xor(q, off); }
    if ((t & 63) == 0) { rs[t >> 6] = s; rq[t >> 6] = q; }
    __syncthreads();
    s = rs[0] + rs[1] + rs[2] + rs[3];
    q = rq[0] + rq[1] + rq[2] + rq[3];
    const float mean = s * (1.f / 512.f);
    const float var  = q * (1.f / 512.f) - mean * mean;
    const float rstd = rsqrtf(var + 1e-5f);
    float2 o;
    o.x = (x0 - mean) * rstd;
    o.y = (x1 - mean) * rstd;
    *reinterpret_cast<float2*>(&out[(size_t)r * 512 + 2 * t]) = o;
}

extern "C" void kernel_launch(void* const* d_in, const int* in_sizes, int n_in,
                              void* d_out, int out_size, void* d_ws, size_t ws_size,
                              hipStream_t stream)
{
    const float* q  = (const float*)d_in[0];
    const float* k  = (const float*)d_in[1];
    const float* v  = (const float*)d_in[2];
    const int*   am = (const int*)d_in[3];
    const int*   sm = (const int*)d_in[4];
    const float* wq = (const float*)d_in[5];
    const float* wk = (const float*)d_in[6];
    const float* wv = (const float*)d_in[7];
    const float* wo = (const float*)d_in[8];

    float* out  = (float*)d_out;                 // [8192,512]
    float* attn = out + (size_t)BB * LL * DD;    // [64,1024,1024]

    unsigned char* W = (unsigned char*)d_ws;
    unsigned short* qbf  = (unsigned short*)(W + 0);
    unsigned short* kbf  = (unsigned short*)(W + 8388608);
    unsigned short* vbf  = (unsigned short*)(W + 16777216);
    unsigned short* wqbf = (unsigned short*)(W + 25165824);
    unsigned short* wkbf = (unsigned short*)(W + 25690112);
    unsigned short* wvbf = (unsigned short*)(W + 26214400);
    unsigned short* wobf = (unsigned short*)(W + 26738688);
    unsigned*       ab   = (unsigned*)      (W + 27262976);
    unsigned*       sb   = (unsigned*)      (W + 28311552);
    unsigned short* Qbf  = (unsigned short*)(W + 29360128);
    unsigned short* Kbf  = (unsigned short*)(W + 37748736);
    unsigned short* Vbf  = (unsigned short*)(W + 46137344);
    // reuse dead regions:
    unsigned short* Vt   = qbf;                       // after proj, qbf dead
    unsigned short* CTXb = kbf;                       // after proj, kbf dead
    float*          X2f  = (float*)(W + 29360128);    // Qbf+Kbf dead after fattn

    cast_kernel<<<dim3(2048, 1, 7), 256, 0, stream>>>(q, k, v, wq, wk, wv, wo,
        qbf, kbf, vbf, wqbf, wkbf, wvbf, wobf);
    maskpack_kernel<<<dim3(32768, 2, 1), 256, 0, stream>>>(am, sm, ab, sb);
    gemm3_kernel<<<dim3(4, 64, 3), 256, 0, stream>>>(qbf, kbf, vbf,
        wqbf, wkbf, wvbf, Qbf, Kbf, Vbf);
    vtrans_kernel<<<dim3(16, 8, 8), 256, 0, stream>>>(Vbf, Vt);
    fattn_kernel<<<dim3(16, 64, 1), 256, 0, stream>>>(Qbf, Kbf, Vt, ab, sb, attn, CTXb);
    gemm1_kernel<<<dim3(4, 64, 1), 256, 0, stream>>>(CTXb, wobf, X2f);
    ln_kernel<<<dim3(8192, 1, 1), 256, 0, stream>>>(X2f, q, out);
}